// Round 10
// baseline (73.178 us; speedup 1.0000x reference)
//
#include <hip/hip_runtime.h>
#include <hip/hip_bf16.h>
#include <math.h>

// NoisyTopExpertsPerItemRouter: B=8,S=4096,D=1024,E=64,K=2
#define B_ 8
#define S_ 4096
#define D_ 1024
#define E_ 64
#define NOISE_STD 0.015625f     // max(1/64, 1e-6)
#define INV_NOISE_STD 64.0f
#define OUT_GATES (B_ * S_ * E_)   // 2097152
#define NBLK 512                   // main grid = S_/8 (64 rows per block)

typedef __attribute__((ext_vector_type(8))) short short8;
typedef __attribute__((ext_vector_type(4))) float f32x4;

// workspace layout (float offsets)
// [0 .. 32768): Wg as bf16 [64][1024] (ushort)
#define WS_GW   32768                    // GW[64]
#define WS_BW   32832                    // BW[64]
#define WS_PART 32896                    // part[512][644] per-block records
#define PART_STRIDE 644                  // 512 imp + 64 sgn + 64 cnt + c1 + c2
#define WS_TOT  (WS_PART + NBLK * PART_STRIDE)
#define N_TOT   642

__device__ __forceinline__ float wave_sum64(float v) {
#pragma unroll
  for (int o = 32; o > 0; o >>= 1) v += __shfl_xor(v, o);
  return v;
}

// ---------------- prep: Wg(bf16) = gamma*W, GW/BW reductions, zero totals ---
__global__ void router_prep(const float* __restrict__ W,
                            const float* __restrict__ gamma,
                            const float* __restrict__ beta,
                            float* __restrict__ ws) {
  if (blockIdx.x >= E_) {
    for (int i = threadIdx.x; i < N_TOT; i += 256) ws[WS_TOT + i] = 0.0f;
    return;
  }
  const int e = blockIdx.x;
  unsigned short* wgb = (unsigned short*)ws;
  float gw = 0.0f, bw = 0.0f;
  for (int d = threadIdx.x; d < D_; d += 256) {
    float wv = W[e * D_ + d];
    float pv = gamma[d] * wv;
    union { __hip_bfloat16 h; unsigned short u; } cv;
    cv.h = __float2bfloat16(pv);
    wgb[e * D_ + d] = cv.u;
    gw += __bfloat162float(cv.h);   // sum of ROUNDED values (consistency)
    bw += beta[d] * wv;
  }
  __shared__ float sred[8];
  gw = wave_sum64(gw);
  bw = wave_sum64(bw);
  const int w = threadIdx.x >> 6, lane = threadIdx.x & 63;
  if (lane == 0) { sred[w] = gw; sred[4 + w] = bw; }
  __syncthreads();
  if (threadIdx.x == 0) {
    ws[WS_GW + e] = sred[0] + sred[1] + sred[2] + sred[3];
    ws[WS_BW + e] = sred[4] + sred[5] + sred[6] + sred[7];
  }
}

// ---------------- main: 64-row blocks, 4-wave B lockstep share, full-K ------
// block = 1024 thr = 16 waves; owns 64 rows (r: b=r&7, sl=r>>3, s=8*bid+sl).
// Wave w: rg=w>>2 (rows 16rg..16rg+15), et=w&3 (experts 16et..16et+15), FULL K
// -> acc = 1 f32x4. The 4 waves sharing et issue IDENTICAL B addresses in
// barrier-lockstep -> L1 serves 3 of 4 (B line traffic halves vs R9).
// X staged once to LDS ([ks][64][33] conflict-free, R5-validated); X reg-queue
// depth 2 + LDS dbuf; B reg-ring 2 steps ahead -> all waits COUNTED vmcnt.
__global__ void __launch_bounds__(1024, 8)
router_main(const float* __restrict__ X, const float* __restrict__ noise,
            float* __restrict__ out, float* __restrict__ ws) {
  __shared__ __align__(16) float unbuf[8704];  // 2 x [2][64][33] staging; -> gcl/gnl
  __shared__ __align__(16) float Lg[4352];     // [64][68] logits; -> pl
  __shared__ float svs[64], sv2s[64];
  __shared__ float cntl[64];
  __shared__ float red16[16];
  float* gcl = unbuf;          // [64][68] clean gates (staging reads done)
  float* gnl = unbuf + 4352;   // [64][68] noisy gates
  float* pl  = Lg;             // per-lane read-then-write -> safe alias

  const int t = threadIdx.x;
  const int w = t >> 6, lane = t & 63;
  const int lrow = lane & 15, kh = lane >> 4;
  const int bid = blockIdx.x;
  const int s0 = bid * 8;

  // staging: thread t -> row r_t = t>>4 (64 rows), dwords c_t..c_t+3 per step
  const int r_t = t >> 4, c_t = (t & 15) * 4;
  const int ks_t = c_t >> 5, cw = c_t & 31;
  const int ldso = ks_t * 2112 + r_t * 33 + cw;
  const float* __restrict__ xstage =
      X + ((size_t)(r_t & 7) * S_ + (size_t)(s0 + (r_t >> 3))) * D_ + c_t;

  // GEMM: wave w -> rg = w>>2, et = w&3
  const int rg = w >> 2, et = w & 3;
  const unsigned short* __restrict__ bp =
      (const unsigned short*)ws + (16 * et + lrow) * D_ + kh * 8;
  const float gwv = ws[WS_GW + 16 * et + lrow];
  const float bwv = ws[WS_BW + 16 * et + lrow];

  // epilogue indices + EARLY noise load (lands during GEMM)
  const int rr_e = lane >> 4, j_e = lane & 15;
  const int r_e = w * 4 + rr_e;                 // [0,64)
  const int b_e = r_e & 7, sl_e = r_e >> 3;
  const int s_e = s0 + sl_e;
  const float4 nv =
      *(const float4*)(noise + ((size_t)b_e * S_ + s_e) * E_ + 4 * j_e);

  // prologue: X regs for steps 0,1; B ring for steps 0,1; stage step 0
  float4 qx[2];
  short8 qb[2][2];
  qx[0] = *(const float4*)(xstage);
  qx[1] = *(const float4*)(xstage + 64);
  qb[0][0] = *(const short8*)(bp);
  qb[0][1] = *(const short8*)(bp + 32);
  qb[1][0] = *(const short8*)(bp + 64);
  qb[1][1] = *(const short8*)(bp + 96);

  float ssv = 0.0f, ssv2 = 0.0f;
  unbuf[ldso + 0] = qx[0].x; unbuf[ldso + 1] = qx[0].y;
  unbuf[ldso + 2] = qx[0].z; unbuf[ldso + 3] = qx[0].w;
  ssv  += (qx[0].x + qx[0].y) + (qx[0].z + qx[0].w);
  ssv2 = fmaf(qx[0].x, qx[0].x, ssv2); ssv2 = fmaf(qx[0].y, qx[0].y, ssv2);
  ssv2 = fmaf(qx[0].z, qx[0].z, ssv2); ssv2 = fmaf(qx[0].w, qx[0].w, ssv2);

  f32x4 acc = {0.f, 0.f, 0.f, 0.f};

#pragma unroll
  for (int s = 0; s < 16; ++s) {
    __syncthreads();                       // buf[s&1] staged
    if (s + 2 < 16)                        // X for step s+2 (slot s&1 now free)
      qx[s & 1] = *(const float4*)(xstage + (s + 2) * 64);

    const float* xb = unbuf + (s & 1) * 4224 + (16 * rg + lrow) * 33 + kh * 8;
#pragma unroll
    for (int ks = 0; ks < 2; ++ks) {
      float4 a0 = *(const float4*)(xb + ks * 2112);
      float4 a1 = *(const float4*)(xb + ks * 2112 + 4);
      union { short8 s8; __hip_bfloat162 h[4]; } u;
      u.h[0] = __float22bfloat162_rn(make_float2(a0.x, a0.y));
      u.h[1] = __float22bfloat162_rn(make_float2(a0.z, a0.w));
      u.h[2] = __float22bfloat162_rn(make_float2(a1.x, a1.y));
      u.h[3] = __float22bfloat162_rn(make_float2(a1.z, a1.w));
      acc = __builtin_amdgcn_mfma_f32_16x16x32_bf16(u.s8, qb[s & 1][ks],
                                                    acc, 0, 0, 0);
    }
    if (s + 2 < 16) {                      // refill B ring slot just consumed
      qb[s & 1][0] = *(const short8*)(bp + (s + 2) * 64);
      qb[s & 1][1] = *(const short8*)(bp + (s + 2) * 64 + 32);
    }
    if (s + 1 < 16) {                      // stage step s+1 (issued at s-1)
      float4 wv = qx[(s + 1) & 1];
      float* d = unbuf + ((s + 1) & 1) * 4224 + ldso;
      d[0] = wv.x; d[1] = wv.y; d[2] = wv.z; d[3] = wv.w;
      ssv  += (wv.x + wv.y) + (wv.z + wv.w);
      ssv2 = fmaf(wv.x, wv.x, ssv2); ssv2 = fmaf(wv.y, wv.y, ssv2);
      ssv2 = fmaf(wv.z, wv.z, ssv2); ssv2 = fmaf(wv.w, wv.w, ssv2);
    }
  }

  // LN stats: 16 staging threads per row -> shfl reduce within 16-lane group
  ssv  += __shfl_xor(ssv, 1);  ssv  += __shfl_xor(ssv, 2);
  ssv  += __shfl_xor(ssv, 4);  ssv  += __shfl_xor(ssv, 8);
  ssv2 += __shfl_xor(ssv2, 1); ssv2 += __shfl_xor(ssv2, 2);
  ssv2 += __shfl_xor(ssv2, 4); ssv2 += __shfl_xor(ssv2, 8);
  if ((t & 15) == 0) { svs[r_t] = ssv; sv2s[r_t] = ssv2; }
  if (t < 64) cntl[t] = 0.0f;
  __syncthreads();

  // logits: C/D layout col=lane&15, row=(lane>>4)*4+i  [m89-verified]
#pragma unroll
  for (int i = 0; i < 4; i++) {
    const int rloc = 16 * rg + kh * 4 + i;
    const float mui = svs[rloc] * (1.0f / (float)D_);
    const float var = sv2s[rloc] * (1.0f / (float)D_) - mui * mui;
    const float rsi = rsqrtf(var + 1e-5f);
    Lg[rloc * 68 + 16 * et + lrow] = rsi * (acc[i] - mui * gwv) + bwv;
  }
  __syncthreads();   // logits ready; staging reads done -> gcl/gnl reusable

  // ---- epilogue: 16 waves; wave w rows 4w..4w+3; lane=(rr,j), 4 experts ----
  {
    const int r = r_e, b = b_e, s = s_e, j = j_e;
    float4 lv = *(const float4*)(Lg + r * 68 + 4 * j);
    float ln0 = fmaf(NOISE_STD, nv.x, lv.x);
    float ln1 = fmaf(NOISE_STD, nv.y, lv.y);
    float ln2 = fmaf(NOISE_STD, nv.z, lv.z);
    float ln3 = fmaf(NOISE_STD, nv.w, lv.w);

    // combined max+secondmax of noisy logits (m1 also shifts clean softmax)
    float m1 = ln0, m2 = -INFINITY;
    m2 = fmaxf(m2, fminf(m1, ln1)); m1 = fmaxf(m1, ln1);
    m2 = fmaxf(m2, fminf(m1, ln2)); m1 = fmaxf(m1, ln2);
    m2 = fmaxf(m2, fminf(m1, ln3)); m1 = fmaxf(m1, ln3);
#pragma unroll
    for (int o = 1; o <= 8; o <<= 1) {
      float o1 = __shfl_xor(m1, o), o2 = __shfl_xor(m2, o);
      m2 = fmaxf(fmaxf(m2, o2), fminf(m1, o1));
      m1 = fmaxf(m1, o1);
    }
    float ec0 = __expf(lv.x - m1), ec1 = __expf(lv.y - m1);
    float ec2 = __expf(lv.z - m1), ec3 = __expf(lv.w - m1);
    float en0 = __expf(ln0 - m1), en1 = __expf(ln1 - m1);
    float en2 = __expf(ln2 - m1), en3 = __expf(ln3 - m1);
    float sg = (ec0 + ec1) + (ec2 + ec3);
    float sn = (en0 + en1) + (en2 + en3);
#pragma unroll
    for (int o = 1; o <= 8; o <<= 1) {
      sg += __shfl_xor(sg, o);
      sn += __shfl_xor(sn, o);
    }
    const float rg_ = 1.0f / sg, rn_ = 1.0f / sn;
    float4 gnv = { en0 * rn_, en1 * rn_, en2 * rn_, en3 * rn_ };
    float4 gcv = { ec0 * rg_, ec1 * rg_, ec2 * rg_, ec3 * rg_ };
    float z0 = fminf(fmaxf((m2 - lv.x) * INV_NOISE_STD, -10.f), 10.f);
    float z1 = fminf(fmaxf((m2 - lv.y) * INV_NOISE_STD, -10.f), 10.f);
    float z2 = fminf(fmaxf((m2 - lv.z) * INV_NOISE_STD, -10.f), 10.f);
    float z3 = fminf(fmaxf((m2 - lv.w) * INV_NOISE_STD, -10.f), 10.f);
    float4 pv = { 0.5f * (1.0f + erff(z0 * 0.70710678118654752f)),
                  0.5f * (1.0f + erff(z1 * 0.70710678118654752f)),
                  0.5f * (1.0f + erff(z2 * 0.70710678118654752f)),
                  0.5f * (1.0f + erff(z3 * 0.70710678118654752f)) };

    *(float4*)(out + ((size_t)b * S_ + s) * E_ + 4 * j) = gnv;
    *(float4*)(gnl + r * 68 + 4 * j) = gnv;
    *(float4*)(gcl + r * 68 + 4 * j) = gcv;
    *(float4*)(pl  + r * 68 + 4 * j) = pv;
    // top-1 count via equality (ties vanishingly rare; softmax is monotone)
    if (ln0 == m1) atomicAdd(&cntl[4 * j + 0], 1.0f);
    if (ln1 == m1) atomicAdd(&cntl[4 * j + 1], 1.0f);
    if (ln2 == m1) atomicAdd(&cntl[4 * j + 2], 1.0f);
    if (ln3 == m1) atomicAdd(&cntl[4 * j + 3], 1.0f);
  }
  __syncthreads();

  // ---- phase 2: block reductions -> PLAIN per-block record (no atomics) ----
  float* prt = ws + WS_PART + (size_t)bid * PART_STRIDE;
  if (t < 512) {
    // importance: (b = t>>6, e = t&63), sum over 8 sl
    const int b0i = t >> 6, e0i = t & 63;
    float v = 0.0f;
#pragma unroll
    for (int sl = 0; sl < 8; sl++) v += gcl[(sl * 8 + b0i) * 68 + e0i];
    prt[t] = v;
    if (t < 64) {
      float sgn = 0.0f;
#pragma unroll
      for (int r = 0; r < 64; r++) sgn += gnl[r * 68 + t];
      prt[512 + t] = sgn;
    } else if (t < 128) {
      prt[576 + (t - 64)] = cntl[t - 64];
    }
  } else {
    const int idx = t - 512;            // [0,512): slc = idx>>6, e = idx&63
    const int slc = idx >> 6, e = idx & 63;
    float P = 0.0f;
#pragma unroll
    for (int b = 0; b < 8; b++) P += pl[(slc * 8 + b) * 68 + e];
    float c1 = P * 0.125f;
    float c2 = c1 * c1;
    c1 = wave_sum64(c1);
    c2 = wave_sum64(c2);
    if (lane == 0) { red16[(w - 8) * 2] = c1; red16[(w - 8) * 2 + 1] = c2; }
  }
  __syncthreads();
  if (t == 0) {
    float c1 = 0.0f, c2 = 0.0f;
#pragma unroll
    for (int i = 0; i < 8; i++) { c1 += red16[2 * i]; c2 += red16[2 * i + 1]; }
    prt[640] = c1;
    prt[641] = c2;
  }
}

// ---------------- reduce: 16 blocks x 32 records, deep unroll ---------------
__global__ void router_reduce(float* __restrict__ ws) {
  const int t = threadIdx.x;
  if (t >= N_TOT) return;
  const int base = blockIdx.x * 32;
  const float* p = ws + WS_PART + (size_t)base * PART_STRIDE + t;
  float acc = 0.0f;
#pragma unroll 8
  for (int i = 0; i < 32; ++i) acc += p[(size_t)i * PART_STRIDE];
  atomicAdd(&ws[WS_TOT + t], acc);
}

// ---------------- finalize: 3 scalar losses from totals ---------------------
__global__ void router_final(const float* __restrict__ ws, float* __restrict__ out) {
  const int lane = threadIdx.x;  // 64 threads = 1 wave
  const float* tot = ws + WS_TOT;
  float impsum = 0.0f;
  for (int b = 0; b < B_; ++b) {
    float v = tot[b * 64 + lane];
    float sfull = wave_sum64(v);
    float mean = sfull * (1.0f / 64.0f);
    float d = v - mean;
    float ss = wave_sum64(d * d);
    impsum += (ss / 63.0f) / (mean * mean);
  }
  float importance = impsum * (1.0f / (float)B_);

  const float N = (float)(S_ * E_);
  float meanp = tot[640] / N;
  float varp = tot[641] / N - meanp * meanp;
  float load = varp / (meanp * meanp);

  const float inv_rows = 1.0f / (float)(B_ * S_);
  float te = (tot[576 + lane] * inv_rows) * (tot[512 + lane] * inv_rows);
  float gs = wave_sum64(te) * (float)E_;

  if (lane == 0) {
    out[OUT_GATES + 0] = importance + load;  // aux (GSHARD_W = 0)
    out[OUT_GATES + 1] = gs;
    out[OUT_GATES + 2] = importance;
    out[OUT_GATES + 3] = load;
  }
}

extern "C" void kernel_launch(void* const* d_in, const int* in_sizes, int n_in,
                              void* d_out, int out_size, void* d_ws, size_t ws_size,
                              hipStream_t stream) {
  (void)in_sizes; (void)n_in; (void)out_size; (void)ws_size;
  const float* X     = (const float*)d_in[0];
  const float* noise = (const float*)d_in[1];
  const float* gamma = (const float*)d_in[2];
  const float* beta  = (const float*)d_in[3];
  const float* W     = (const float*)d_in[4];
  float* out = (float*)d_out;
  float* ws  = (float*)d_ws;

  router_prep<<<dim3(E_ + 1), dim3(256), 0, stream>>>(W, gamma, beta, ws);
  router_main<<<dim3(NBLK), dim3(1024), 0, stream>>>(X, noise, out, ws);
  router_reduce<<<dim3(16), dim3(704), 0, stream>>>(ws);
  router_final<<<dim3(1), dim3(64), 0, stream>>>(ws, out);
}

// Round 11
// 70.718 us; speedup vs baseline: 1.0348x; 1.0348x over previous
//
#include <hip/hip_runtime.h>
#include <hip/hip_bf16.h>
#include <math.h>

// NoisyTopExpertsPerItemRouter: B=8,S=4096,D=1024,E=64,K=2
#define B_ 8
#define S_ 4096
#define D_ 1024
#define E_ 64
#define NOISE_STD 0.015625f     // max(1/64, 1e-6)
#define INV_NOISE_STD 64.0f
#define OUT_GATES (B_ * S_ * E_)   // 2097152
#define NBLK 512                   // main grid = S_/8 (64 rows per block)

typedef __attribute__((ext_vector_type(8))) short short8;
typedef __attribute__((ext_vector_type(4))) float f32x4;

// workspace layout (float offsets)
// [0 .. 32768): Wg as bf16 [64][1024] (ushort)
#define WS_GW   32768                    // GW[64]
#define WS_BW   32832                    // BW[64]
#define WS_PART 32896                    // part[512][644] per-block records
#define PART_STRIDE 644                  // 512 imp + 64 sgn + 64 cnt + c1 + c2
#define WS_TOT  (WS_PART + NBLK * PART_STRIDE)
#define N_TOT   642

__device__ __forceinline__ float wave_sum64(float v) {
#pragma unroll
  for (int o = 32; o > 0; o >>= 1) v += __shfl_xor(v, o);
  return v;
}

// ---------------- prep: Wg(bf16) = gamma*W, GW/BW reductions, zero totals ---
__global__ void router_prep(const float* __restrict__ W,
                            const float* __restrict__ gamma,
                            const float* __restrict__ beta,
                            float* __restrict__ ws) {
  if (blockIdx.x >= E_) {
    for (int i = threadIdx.x; i < N_TOT; i += 256) ws[WS_TOT + i] = 0.0f;
    return;
  }
  const int e = blockIdx.x;
  unsigned short* wgb = (unsigned short*)ws;
  float gw = 0.0f, bw = 0.0f;
  for (int d = threadIdx.x; d < D_; d += 256) {
    float wv = W[e * D_ + d];
    float pv = gamma[d] * wv;
    union { __hip_bfloat16 h; unsigned short u; } cv;
    cv.h = __float2bfloat16(pv);
    wgb[e * D_ + d] = cv.u;
    gw += __bfloat162float(cv.h);   // sum of ROUNDED values (consistency)
    bw += beta[d] * wv;
  }
  __shared__ float sred[8];
  gw = wave_sum64(gw);
  bw = wave_sum64(bw);
  const int w = threadIdx.x >> 6, lane = threadIdx.x & 63;
  if (lane == 0) { sred[w] = gw; sred[4 + w] = bw; }
  __syncthreads();
  if (threadIdx.x == 0) {
    ws[WS_GW + e] = sred[0] + sred[1] + sred[2] + sred[3];
    ws[WS_BW + e] = sred[4] + sred[5] + sred[6] + sred[7];
  }
}

// ---------------- main: 64-row blocks, 8 waves, B reg-reuse across 2 halves -
// block = 512 thr = 8 waves; owns 64 rows (r: b=r&7, sl=r>>3, s=8*bid+sl).
// Wave w: et=w&3 (experts 16et..16et+15), rh=w>>2 -> TWO 16-row groups
// (rows 32rh..32rh+15 and 32rh+16..32rh+31), FULL K, 2 accumulators; each
// B-fragment is loaded ONCE and feeds 2 MFMAs (register reuse). Waves w,w+4
// share et in barrier-lockstep -> L1 serves the duplicate B stream. X staged
// to LDS [2 bufs][2 ks][64][33] (conflict-free, R5-validated); X reg-queue
// depth 2 (per row) + B ring 2 steps ahead -> all waits COUNTED vmcnt.
__global__ void __launch_bounds__(512, 4)
router_main(const float* __restrict__ X, const float* __restrict__ noise,
            float* __restrict__ out, float* __restrict__ ws) {
  __shared__ __align__(16) float unbuf[8704];  // staging 2x4224; -> gcl/gnl
  __shared__ __align__(16) float Lg[4352];     // [64][68] logits; -> pl
  __shared__ float svs[64], sv2s[64];
  __shared__ float cntl[64];
  __shared__ float red8[16];
  float* gcl = unbuf;          // [64][68] clean gates (staging reads done)
  float* gnl = unbuf + 4352;   // [64][68] noisy gates
  float* pl  = Lg;             // per-lane read-then-write -> safe alias

  const int t = threadIdx.x;
  const int w = t >> 6, lane = t & 63;
  const int lrow = lane & 15, kh = lane >> 4;
  const int bid = blockIdx.x;
  const int s0 = bid * 8;

  // staging: thread t -> rows r0=t>>4 and r1=r0+32, dwords c_t..c_t+3 per step
  const int r0 = t >> 4, r1 = r0 + 32, c_t = (t & 15) * 4;
  const int ks_t = c_t >> 5, cw = c_t & 31;
  const int ldso0 = ks_t * 2112 + r0 * 33 + cw;
  const int ldso1 = ks_t * 2112 + r1 * 33 + cw;
  const float* __restrict__ xstage0 =
      X + ((size_t)(r0 & 7) * S_ + (size_t)(s0 + (r0 >> 3))) * D_ + c_t;
  const float* __restrict__ xstage1 =
      X + ((size_t)(r1 & 7) * S_ + (size_t)(s0 + (r1 >> 3))) * D_ + c_t;

  // GEMM: wave w -> et = w&3, rh = w>>2; rows rA=32rh+lrow, rB=rA+16
  const int et = w & 3, rh = w >> 2;
  const int rA = 32 * rh + lrow;
  const unsigned short* __restrict__ bp =
      (const unsigned short*)ws + (16 * et + lrow) * D_ + kh * 8;
  const float gwv = ws[WS_GW + 16 * et + lrow];
  const float bwv = ws[WS_BW + 16 * et + lrow];

  // epilogue indices + EARLY noise loads (land during GEMM)
  const int rr_e = lane >> 4, j_e = lane & 15;
  const int re0 = 8 * w + rr_e, re1 = 8 * w + 4 + rr_e;
  const int be0 = re0 & 7, se0 = s0 + (re0 >> 3);
  const int be1 = re1 & 7, se1 = s0 + (re1 >> 3);
  const float4 nv0 =
      *(const float4*)(noise + ((size_t)be0 * S_ + se0) * E_ + 4 * j_e);
  const float4 nv1 =
      *(const float4*)(noise + ((size_t)be1 * S_ + se1) * E_ + 4 * j_e);

  // prologue: X regs steps 0,1 (both rows); B ring steps 0,1; stage step 0
  float4 qx0[2], qx1[2];
  short8 qb[2][2];
  qx0[0] = *(const float4*)(xstage0);
  qx1[0] = *(const float4*)(xstage1);
  qx0[1] = *(const float4*)(xstage0 + 64);
  qx1[1] = *(const float4*)(xstage1 + 64);
  qb[0][0] = *(const short8*)(bp);
  qb[0][1] = *(const short8*)(bp + 32);
  qb[1][0] = *(const short8*)(bp + 64);
  qb[1][1] = *(const short8*)(bp + 96);

  float sa0 = 0.0f, sq0 = 0.0f, sa1 = 0.0f, sq1 = 0.0f;
  {
    float4 v = qx0[0];
    unbuf[ldso0 + 0] = v.x; unbuf[ldso0 + 1] = v.y;
    unbuf[ldso0 + 2] = v.z; unbuf[ldso0 + 3] = v.w;
    sa0 += (v.x + v.y) + (v.z + v.w);
    sq0 = fmaf(v.x, v.x, sq0); sq0 = fmaf(v.y, v.y, sq0);
    sq0 = fmaf(v.z, v.z, sq0); sq0 = fmaf(v.w, v.w, sq0);
    v = qx1[0];
    unbuf[ldso1 + 0] = v.x; unbuf[ldso1 + 1] = v.y;
    unbuf[ldso1 + 2] = v.z; unbuf[ldso1 + 3] = v.w;
    sa1 += (v.x + v.y) + (v.z + v.w);
    sq1 = fmaf(v.x, v.x, sq1); sq1 = fmaf(v.y, v.y, sq1);
    sq1 = fmaf(v.z, v.z, sq1); sq1 = fmaf(v.w, v.w, sq1);
  }

  f32x4 accA = {0.f, 0.f, 0.f, 0.f};
  f32x4 accB = {0.f, 0.f, 0.f, 0.f};

#pragma unroll
  for (int s = 0; s < 16; ++s) {
    __syncthreads();                       // buf[s&1] staged
    if (s + 2 < 16) {                      // X for step s+2 (slot s&1 free)
      qx0[s & 1] = *(const float4*)(xstage0 + (s + 2) * 64);
      qx1[s & 1] = *(const float4*)(xstage1 + (s + 2) * 64);
    }
    const float* xbA = unbuf + (s & 1) * 4224 + rA * 33 + kh * 8;
#pragma unroll
    for (int ks = 0; ks < 2; ++ks) {
      float4 a0 = *(const float4*)(xbA + ks * 2112);
      float4 a1 = *(const float4*)(xbA + ks * 2112 + 4);
      float4 b0 = *(const float4*)(xbA + ks * 2112 + 16 * 33);
      float4 b1 = *(const float4*)(xbA + ks * 2112 + 16 * 33 + 4);
      union { short8 s8; __hip_bfloat162 h[4]; } uA, uB;
      uA.h[0] = __float22bfloat162_rn(make_float2(a0.x, a0.y));
      uA.h[1] = __float22bfloat162_rn(make_float2(a0.z, a0.w));
      uA.h[2] = __float22bfloat162_rn(make_float2(a1.x, a1.y));
      uA.h[3] = __float22bfloat162_rn(make_float2(a1.z, a1.w));
      uB.h[0] = __float22bfloat162_rn(make_float2(b0.x, b0.y));
      uB.h[1] = __float22bfloat162_rn(make_float2(b0.z, b0.w));
      uB.h[2] = __float22bfloat162_rn(make_float2(b1.x, b1.y));
      uB.h[3] = __float22bfloat162_rn(make_float2(b1.z, b1.w));
      accA = __builtin_amdgcn_mfma_f32_16x16x32_bf16(uA.s8, qb[s & 1][ks],
                                                     accA, 0, 0, 0);
      accB = __builtin_amdgcn_mfma_f32_16x16x32_bf16(uB.s8, qb[s & 1][ks],
                                                     accB, 0, 0, 0);
    }
    if (s + 2 < 16) {                      // refill B ring slot just consumed
      qb[s & 1][0] = *(const short8*)(bp + (s + 2) * 64);
      qb[s & 1][1] = *(const short8*)(bp + (s + 2) * 64 + 32);
    }
    if (s + 1 < 16) {                      // stage step s+1 (issued at s-1)
      float4 v = qx0[(s + 1) & 1];
      float* d = unbuf + ((s + 1) & 1) * 4224 + ldso0;
      d[0] = v.x; d[1] = v.y; d[2] = v.z; d[3] = v.w;
      sa0 += (v.x + v.y) + (v.z + v.w);
      sq0 = fmaf(v.x, v.x, sq0); sq0 = fmaf(v.y, v.y, sq0);
      sq0 = fmaf(v.z, v.z, sq0); sq0 = fmaf(v.w, v.w, sq0);
      v = qx1[(s + 1) & 1];
      d = unbuf + ((s + 1) & 1) * 4224 + ldso1;
      d[0] = v.x; d[1] = v.y; d[2] = v.z; d[3] = v.w;
      sa1 += (v.x + v.y) + (v.z + v.w);
      sq1 = fmaf(v.x, v.x, sq1); sq1 = fmaf(v.y, v.y, sq1);
      sq1 = fmaf(v.z, v.z, sq1); sq1 = fmaf(v.w, v.w, sq1);
    }
  }

  // LN stats: 16 staging threads per row -> shfl reduce within 16-lane group
  sa0 += __shfl_xor(sa0, 1); sa0 += __shfl_xor(sa0, 2);
  sa0 += __shfl_xor(sa0, 4); sa0 += __shfl_xor(sa0, 8);
  sq0 += __shfl_xor(sq0, 1); sq0 += __shfl_xor(sq0, 2);
  sq0 += __shfl_xor(sq0, 4); sq0 += __shfl_xor(sq0, 8);
  sa1 += __shfl_xor(sa1, 1); sa1 += __shfl_xor(sa1, 2);
  sa1 += __shfl_xor(sa1, 4); sa1 += __shfl_xor(sa1, 8);
  sq1 += __shfl_xor(sq1, 1); sq1 += __shfl_xor(sq1, 2);
  sq1 += __shfl_xor(sq1, 4); sq1 += __shfl_xor(sq1, 8);
  if ((t & 15) == 0) {
    svs[r0] = sa0; sv2s[r0] = sq0;
    svs[r1] = sa1; sv2s[r1] = sq1;
  }
  if (t < 64) cntl[t] = 0.0f;
  __syncthreads();

  // logits: C/D layout col=lane&15, row=(lane>>4)*4+i  [m89-verified]
#pragma unroll
  for (int i = 0; i < 4; i++) {
    const int rlA = 32 * rh + kh * 4 + i;
    const int rlB = rlA + 16;
    float muA = svs[rlA] * (1.0f / (float)D_);
    float vrA = sv2s[rlA] * (1.0f / (float)D_) - muA * muA;
    float rsA = rsqrtf(vrA + 1e-5f);
    Lg[rlA * 68 + 16 * et + lrow] = rsA * (accA[i] - muA * gwv) + bwv;
    float muB = svs[rlB] * (1.0f / (float)D_);
    float vrB = sv2s[rlB] * (1.0f / (float)D_) - muB * muB;
    float rsB = rsqrtf(vrB + 1e-5f);
    Lg[rlB * 68 + 16 * et + lrow] = rsB * (accB[i] - muB * gwv) + bwv;
  }
  __syncthreads();   // logits ready; staging reads done -> gcl/gnl reusable

  // ---- epilogue: 8 waves x 2 passes; wave w rows 8w..8w+7; lane=(rr,j) ----
#pragma unroll
  for (int ep = 0; ep < 2; ++ep) {
    const int r = ep ? re1 : re0;
    const int b = ep ? be1 : be0;
    const int s = ep ? se1 : se0;
    const float4 nv = ep ? nv1 : nv0;
    const int j = j_e;
    float4 lv = *(const float4*)(Lg + r * 68 + 4 * j);
    float ln0 = fmaf(NOISE_STD, nv.x, lv.x);
    float ln1 = fmaf(NOISE_STD, nv.y, lv.y);
    float ln2 = fmaf(NOISE_STD, nv.z, lv.z);
    float ln3 = fmaf(NOISE_STD, nv.w, lv.w);

    // combined max+secondmax of noisy logits (m1 also shifts clean softmax)
    float m1 = ln0, m2 = -INFINITY;
    m2 = fmaxf(m2, fminf(m1, ln1)); m1 = fmaxf(m1, ln1);
    m2 = fmaxf(m2, fminf(m1, ln2)); m1 = fmaxf(m1, ln2);
    m2 = fmaxf(m2, fminf(m1, ln3)); m1 = fmaxf(m1, ln3);
#pragma unroll
    for (int o = 1; o <= 8; o <<= 1) {
      float o1 = __shfl_xor(m1, o), o2 = __shfl_xor(m2, o);
      m2 = fmaxf(fmaxf(m2, o2), fminf(m1, o1));
      m1 = fmaxf(m1, o1);
    }
    float ec0 = __expf(lv.x - m1), ec1 = __expf(lv.y - m1);
    float ec2 = __expf(lv.z - m1), ec3 = __expf(lv.w - m1);
    float en0 = __expf(ln0 - m1), en1 = __expf(ln1 - m1);
    float en2 = __expf(ln2 - m1), en3 = __expf(ln3 - m1);
    float sg = (ec0 + ec1) + (ec2 + ec3);
    float sn = (en0 + en1) + (en2 + en3);
#pragma unroll
    for (int o = 1; o <= 8; o <<= 1) {
      sg += __shfl_xor(sg, o);
      sn += __shfl_xor(sn, o);
    }
    const float rg_ = 1.0f / sg, rn_ = 1.0f / sn;
    float4 gnv = { en0 * rn_, en1 * rn_, en2 * rn_, en3 * rn_ };
    float4 gcv = { ec0 * rg_, ec1 * rg_, ec2 * rg_, ec3 * rg_ };
    float z0 = fminf(fmaxf((m2 - lv.x) * INV_NOISE_STD, -10.f), 10.f);
    float z1 = fminf(fmaxf((m2 - lv.y) * INV_NOISE_STD, -10.f), 10.f);
    float z2 = fminf(fmaxf((m2 - lv.z) * INV_NOISE_STD, -10.f), 10.f);
    float z3 = fminf(fmaxf((m2 - lv.w) * INV_NOISE_STD, -10.f), 10.f);
    float4 pv = { 0.5f * (1.0f + erff(z0 * 0.70710678118654752f)),
                  0.5f * (1.0f + erff(z1 * 0.70710678118654752f)),
                  0.5f * (1.0f + erff(z2 * 0.70710678118654752f)),
                  0.5f * (1.0f + erff(z3 * 0.70710678118654752f)) };

    *(float4*)(out + ((size_t)b * S_ + s) * E_ + 4 * j) = gnv;
    *(float4*)(gnl + r * 68 + 4 * j) = gnv;
    *(float4*)(gcl + r * 68 + 4 * j) = gcv;
    *(float4*)(pl  + r * 68 + 4 * j) = pv;
    // top-1 count via equality (ties vanishingly rare; softmax is monotone)
    if (ln0 == m1) atomicAdd(&cntl[4 * j + 0], 1.0f);
    if (ln1 == m1) atomicAdd(&cntl[4 * j + 1], 1.0f);
    if (ln2 == m1) atomicAdd(&cntl[4 * j + 2], 1.0f);
    if (ln3 == m1) atomicAdd(&cntl[4 * j + 3], 1.0f);
  }
  __syncthreads();

  // ---- phase 2: block reductions -> PLAIN per-block record (no atomics) ----
  float* prt = ws + WS_PART + (size_t)bid * PART_STRIDE;
  {
    // importance: (b = t>>6, e = t&63), sum over 8 sl
    const int b0i = t >> 6, e0i = t & 63;
    float v = 0.0f;
#pragma unroll
    for (int sl = 0; sl < 8; sl++) v += gcl[(sl * 8 + b0i) * 68 + e0i];
    prt[t] = v;
  }
  {
    // p_mean stats: (slc = t>>6, e = t&63): P = sum_b p
    const int slc = t >> 6, e = t & 63;
    float P = 0.0f;
#pragma unroll
    for (int b = 0; b < 8; b++) P += pl[(slc * 8 + b) * 68 + e];
    float c1 = P * 0.125f;
    float c2 = c1 * c1;
    c1 = wave_sum64(c1);
    c2 = wave_sum64(c2);
    if (lane == 0) { red8[w * 2] = c1; red8[w * 2 + 1] = c2; }
  }
  if (t < 64) {
    float sgn = 0.0f;
#pragma unroll
    for (int r = 0; r < 64; r++) sgn += gnl[r * 68 + t];
    prt[512 + t] = sgn;
  } else if (t < 128) {
    prt[576 + (t - 64)] = cntl[t - 64];
  }
  __syncthreads();
  if (t == 0) {
    float c1 = 0.0f, c2 = 0.0f;
#pragma unroll
    for (int i = 0; i < 8; i++) { c1 += red8[2 * i]; c2 += red8[2 * i + 1]; }
    prt[640] = c1;
    prt[641] = c2;
  }
}

// ---------------- reduce: 16 blocks x 32 records, deep unroll ---------------
__global__ void router_reduce(float* __restrict__ ws) {
  const int t = threadIdx.x;
  if (t >= N_TOT) return;
  const int base = blockIdx.x * 32;
  const float* p = ws + WS_PART + (size_t)base * PART_STRIDE + t;
  float acc = 0.0f;
#pragma unroll 8
  for (int i = 0; i < 32; ++i) acc += p[(size_t)i * PART_STRIDE];
  atomicAdd(&ws[WS_TOT + t], acc);
}

// ---------------- finalize: 3 scalar losses from totals ---------------------
__global__ void router_final(const float* __restrict__ ws, float* __restrict__ out) {
  const int lane = threadIdx.x;  // 64 threads = 1 wave
  const float* tot = ws + WS_TOT;
  float impsum = 0.0f;
  for (int b = 0; b < B_; ++b) {
    float v = tot[b * 64 + lane];
    float sfull = wave_sum64(v);
    float mean = sfull * (1.0f / 64.0f);
    float d = v - mean;
    float ss = wave_sum64(d * d);
    impsum += (ss / 63.0f) / (mean * mean);
  }
  float importance = impsum * (1.0f / (float)B_);

  const float N = (float)(S_ * E_);
  float meanp = tot[640] / N;
  float varp = tot[641] / N - meanp * meanp;
  float load = varp / (meanp * meanp);

  const float inv_rows = 1.0f / (float)(B_ * S_);
  float te = (tot[576 + lane] * inv_rows) * (tot[512 + lane] * inv_rows);
  float gs = wave_sum64(te) * (float)E_;

  if (lane == 0) {
    out[OUT_GATES + 0] = importance + load;  // aux (GSHARD_W = 0)
    out[OUT_GATES + 1] = gs;
    out[OUT_GATES + 2] = importance;
    out[OUT_GATES + 3] = load;
  }
}

extern "C" void kernel_launch(void* const* d_in, const int* in_sizes, int n_in,
                              void* d_out, int out_size, void* d_ws, size_t ws_size,
                              hipStream_t stream) {
  (void)in_sizes; (void)n_in; (void)out_size; (void)ws_size;
  const float* X     = (const float*)d_in[0];
  const float* noise = (const float*)d_in[1];
  const float* gamma = (const float*)d_in[2];
  const float* beta  = (const float*)d_in[3];
  const float* W     = (const float*)d_in[4];
  float* out = (float*)d_out;
  float* ws  = (float*)d_ws;

  router_prep<<<dim3(E_ + 1), dim3(256), 0, stream>>>(W, gamma, beta, ws);
  router_main<<<dim3(NBLK), dim3(512), 0, stream>>>(X, noise, out, ws);
  router_reduce<<<dim3(16), dim3(704), 0, stream>>>(ws);
  router_final<<<dim3(1), dim3(64), 0, stream>>>(ws, out);
}